// Round 1
// baseline (88.697 us; speedup 1.0000x reference)
//
#include <hip/hip_runtime.h>

// Problem constants (match reference setup_inputs)
namespace {
constexpr int B   = 64;
constexpr int S   = 128;
constexpr int Wd  = 32;    // words per text segment
constexpr int T   = 128;   // law segments
constexpr int D   = 200;   // embedding dim
constexpr int SEGS = 4;            // segments per gather block
constexpr int CHB  = S / SEGS;     // 32 chunks per batch
constexpr int CHL  = T / SEGS;     // 32 law chunks
constexpr int NTXT = B * CHB;      // 2048 text blocks
}

// Kernel 1: gather embedding rows and accumulate partial sums.
// Blocks [0, NTXT)        -> text chunk (b, chunk): sum over valid rows of 4 segments
// Blocks [NTXT, NTXT+CHL) -> law chunk: sum over 4 law segments' rows
__global__ void gather_sum_kernel(const int* __restrict__ text_ids,
                                  const int* __restrict__ text_lens,
                                  const int* __restrict__ law_ids,
                                  const float* __restrict__ emb,
                                  float* __restrict__ fact_part,   // [NTXT][D]
                                  float* __restrict__ law_part) {  // [CHL][D]
  __shared__ int ids[SEGS * Wd];   // 128 row ids (-1 = skip)
  const int tid = threadIdx.x;
  const int blk = blockIdx.x;
  const bool isLaw = (blk >= NTXT);

  if (tid < SEGS * Wd) {
    const int sl = tid >> 5;   // local segment 0..3
    const int w  = tid & 31;
    int id;
    if (isLaw) {
      const int chunk = blk - NTXT;
      id = law_ids[(chunk * SEGS + sl) * Wd + w];
    } else {
      const int b = blk / CHB;
      const int chunk = blk % CHB;
      const int s = chunk * SEGS + sl;
      id = (s < text_lens[b]) ? text_ids[(b * S + s) * Wd + w] : -1;
    }
    ids[tid] = id;
  }
  __syncthreads();

  const int d = tid;
  if (d >= D) return;   // 200 of 256 lanes active; memory-bound, acceptable
  float a0 = 0.f, a1 = 0.f, a2 = 0.f, a3 = 0.f;
  for (int r = 0; r < SEGS * Wd; r += 4) {
    const int i0 = ids[r + 0];
    const int i1 = ids[r + 1];
    const int i2 = ids[r + 2];
    const int i3 = ids[r + 3];
    // ids are wave-uniform -> uniform branches, coalesced 800B row reads
    if (i0 >= 0) a0 += emb[(size_t)i0 * D + d];
    if (i1 >= 0) a1 += emb[(size_t)i1 * D + d];
    if (i2 >= 0) a2 += emb[(size_t)i2 * D + d];
    if (i3 >= 0) a3 += emb[(size_t)i3 * D + d];
  }
  const float acc = (a0 + a1) + (a2 + a3);
  if (isLaw) law_part[(size_t)(blk - NTXT) * D + d] = acc;
  else       fact_part[(size_t)blk * D + d] = acc;
}

// Kernel 2: reduce partials -> feat[400], FC head + softmax, plus constant
// avg_alpha output. One block per batch element, 512 threads.
__global__ void head_kernel(const float* __restrict__ fact_part,
                            const float* __restrict__ law_part,
                            const float* __restrict__ W1,
                            const float* __restrict__ b1,
                            const float* __restrict__ W2,
                            const float* __restrict__ b2,
                            float* __restrict__ out) {
  __shared__ float feat[2 * D];   // [fact(200) | label(200)]
  __shared__ float hbuf[2 * D];
  __shared__ float logits[6];
  const int b = blockIdx.x;
  const int tid = threadIdx.x;
  // (1 + 1/T) * (1/S) * (1/Wd)  ==  (1 + 1/S) * (1/T) * (1/Wd)
  constexpr float CC = (129.0f / 128.0f) / 4096.0f;

  // avg_alpha == 1/T exactly (softmax row mean). Output region [B*6, B*6+B*S).
  if (tid < S) out[B * 6 + b * S + tid] = 1.0f / 128.0f;

  if (tid < D) {
    float s = 0.f;
    for (int k = 0; k < CHB; ++k) s += fact_part[(size_t)(b * CHB + k) * D + tid];
    feat[tid] = s * CC;
  } else if (tid >= 256 && tid < 256 + D) {
    const int d = tid - 256;
    float s = 0.f;
    for (int k = 0; k < CHL; ++k) s += law_part[(size_t)k * D + d];
    feat[D + d] = s * CC;
  }
  __syncthreads();

  // h = relu(feat @ W1 + b1); thread j owns column j (coalesced W1 reads)
  if (tid < 2 * D) {
    float acc = b1[tid];
    for (int i = 0; i < 2 * D; ++i)
      acc = fmaf(feat[i], W1[(size_t)i * (2 * D) + tid], acc);
    hbuf[tid] = fmaxf(acc, 0.f);
  }
  __syncthreads();

  // logits = h @ W2 + b2 (6 columns)
  if (tid < 6) {
    float acc = b2[tid];
    for (int j = 0; j < 2 * D; ++j)
      acc = fmaf(hbuf[j], W2[(size_t)j * 6 + tid], acc);
    logits[tid] = acc;
  }
  __syncthreads();

  // softmax over 6 logits
  if (tid == 0) {
    float m = logits[0];
    for (int k = 1; k < 6; ++k) m = fmaxf(m, logits[k]);
    float e[6];
    float ssum = 0.f;
    for (int k = 0; k < 6; ++k) { e[k] = expf(logits[k] - m); ssum += e[k]; }
    const float inv = 1.0f / ssum;
    for (int k = 0; k < 6; ++k) out[b * 6 + k] = e[k] * inv;
  }
}

extern "C" void kernel_launch(void* const* d_in, const int* in_sizes, int n_in,
                              void* d_out, int out_size, void* d_ws, size_t ws_size,
                              hipStream_t stream) {
  const int*   text_ids  = (const int*)d_in[0];
  const int*   text_lens = (const int*)d_in[1];
  const int*   law_ids   = (const int*)d_in[2];
  const float* emb       = (const float*)d_in[3];
  const float* W1        = (const float*)d_in[4];
  const float* b1        = (const float*)d_in[5];
  const float* W2        = (const float*)d_in[6];
  const float* b2        = (const float*)d_in[7];
  float* out = (float*)d_out;

  float* fact_part = (float*)d_ws;                     // NTXT * D floats
  float* law_part  = fact_part + (size_t)NTXT * D;     // CHL * D floats
  // total ws use: (2048 + 32) * 200 * 4 B = 1.664 MB

  hipLaunchKernelGGL(gather_sum_kernel, dim3(NTXT + CHL), dim3(256), 0, stream,
                     text_ids, text_lens, law_ids, emb, fact_part, law_part);
  hipLaunchKernelGGL(head_kernel, dim3(B), dim3(512), 0, stream,
                     fact_part, law_part, W1, b1, W2, b2, out);
}

// Round 2
// 35.895 us; speedup vs baseline: 2.4710x; 2.4710x over previous
//
#include <hip/hip_runtime.h>

// Problem constants (match reference setup_inputs)
namespace {
constexpr int B   = 64;
constexpr int S   = 128;
constexpr int Wd  = 32;    // words per text segment
constexpr int T   = 128;   // law segments
constexpr int D   = 200;   // embedding dim
constexpr int SEGS = 4;            // segments per gather block
constexpr int CHB  = S / SEGS;     // 32 chunks per batch
constexpr int CHL  = T / SEGS;     // 32 law chunks
constexpr int NTXT = B * CHB;      // 2048 text blocks
// (1 + 1/T) * (1/S) * (1/Wd) == (1 + 1/S) * (1/T) * (1/Wd): softmax-mean
// collapse makes avg_alpha == 1/T and avg_beta == 1/S exactly.
constexpr float CC = (129.0f / 128.0f) / 4096.0f;
using f32x4 = __attribute__((ext_vector_type(4))) float;
}

// Kernel 1: gather embedding rows, accumulate partial sums.
// Each wave loads WHOLE rows (50 lanes x float4 = 800B per instruction);
// 4 waves split the 128 rows of the chunk; branch-free masked accumulate
// so the compiler can keep many rows in flight.
__global__ void gather_sum_kernel(const int* __restrict__ text_ids,
                                  const int* __restrict__ text_lens,
                                  const int* __restrict__ law_ids,
                                  const float* __restrict__ emb,
                                  float* __restrict__ fact_part,   // [NTXT][D]
                                  float* __restrict__ law_part) {  // [CHL][D]
  __shared__ int ids[SEGS * Wd];                 // 128 row ids (-1 = skip)
  __shared__ __align__(16) float wsum[4][D];     // per-wave partials
  const int tid = threadIdx.x;
  const int blk = blockIdx.x;
  const bool isLaw = (blk >= NTXT);
  const int b = blk / CHB;         // valid only for text blocks
  const int chunk = blk % CHB;

  if (!isLaw) {
    const int len = text_lens[b];
    if (chunk * SEGS >= len) {     // fully-invalid chunk: zero and leave
      if (tid < D) fact_part[(size_t)blk * D + tid] = 0.f;
      return;
    }
    if (tid < SEGS * Wd) {
      const int s = chunk * SEGS + (tid >> 5);
      ids[tid] = (s < len) ? text_ids[((size_t)b * S + s) * Wd + (tid & 31)] : -1;
    }
  } else {
    if (tid < SEGS * Wd) ids[tid] = law_ids[(size_t)(blk - NTXT) * (SEGS * Wd) + tid];
  }
  __syncthreads();

  const int w = tid >> 6;      // wave 0..3 -> rows [w*32, w*32+32)
  const int lane = tid & 63;
  const f32x4* __restrict__ embv = reinterpret_cast<const f32x4*>(emb);
  if (lane < 50) {
    f32x4 a0 = 0.f, a1 = 0.f, a2 = 0.f, a3 = 0.f;
    #pragma unroll
    for (int r = 0; r < 32; r += 4) {
      const int i0 = ids[w * 32 + r + 0];
      const int i1 = ids[w * 32 + r + 1];
      const int i2 = ids[w * 32 + r + 2];
      const int i3 = ids[w * 32 + r + 3];
      // branch-free: invalid rows read row 0 (L1-resident) and add 0
      const float m0 = (i0 >= 0) ? 1.f : 0.f;
      const float m1 = (i1 >= 0) ? 1.f : 0.f;
      const float m2 = (i2 >= 0) ? 1.f : 0.f;
      const float m3 = (i3 >= 0) ? 1.f : 0.f;
      const size_t r0 = (size_t)(i0 >= 0 ? i0 : 0) * 50 + lane;
      const size_t r1 = (size_t)(i1 >= 0 ? i1 : 0) * 50 + lane;
      const size_t r2 = (size_t)(i2 >= 0 ? i2 : 0) * 50 + lane;
      const size_t r3 = (size_t)(i3 >= 0 ? i3 : 0) * 50 + lane;
      a0 += embv[r0] * m0;
      a1 += embv[r1] * m1;
      a2 += embv[r2] * m2;
      a3 += embv[r3] * m3;
    }
    *reinterpret_cast<f32x4*>(&wsum[w][lane * 4]) = (a0 + a1) + (a2 + a3);
  }
  __syncthreads();

  if (tid < D) {
    const float rv = (wsum[0][tid] + wsum[1][tid]) + (wsum[2][tid] + wsum[3][tid]);
    if (isLaw) law_part[(size_t)(blk - NTXT) * D + tid] = rv;
    else       fact_part[(size_t)blk * D + tid] = rv;
  }
}

// Kernel 2: per-(batch, i-quarter) partial GEMV through W1.
// 256 blocks -> whole chip busy; each block streams only 100 rows of W1.
__global__ void gemv_part_kernel(const float* __restrict__ fact_part,
                                 const float* __restrict__ law_part,
                                 const float* __restrict__ W1,
                                 float* __restrict__ hpart) {  // [B*4][400]
  __shared__ float red[4][100];
  __shared__ float featq[100];
  const int bq = blockIdx.x;
  const int b = bq >> 2;
  const int q = bq & 3;            // i-quarter: global i in [q*100, q*100+100)
  const int tid = threadIdx.x;

  if (tid < 400) {
    const int il = tid % 100;      // i within quarter
    const int kg = tid / 100;      // chunk-group 0..3 (8 chunks each)
    const int ig = q * 100 + il;   // global feat index
    const float* p = (ig < 2 * D / 2)  // ig < 200 -> fact, else label
        ? fact_part + ((size_t)b * CHB + kg * 8) * D + ig
        : law_part + (size_t)(kg * 8) * D + (ig - D);
    float s = 0.f;
    #pragma unroll
    for (int k = 0; k < 8; ++k) s += p[(size_t)k * D];
    red[kg][il] = s;
  }
  __syncthreads();
  if (tid < 100)
    featq[tid] = ((red[0][tid] + red[1][tid]) + (red[2][tid] + red[3][tid])) * CC;
  __syncthreads();

  if (tid < 400) {
    const float* Wp = W1 + (size_t)(q * 100) * 400 + tid;  // column tid
    float c0 = 0.f, c1 = 0.f, c2 = 0.f, c3 = 0.f;
    #pragma unroll
    for (int i = 0; i < 100; i += 4) {
      c0 = fmaf(featq[i + 0], Wp[(size_t)(i + 0) * 400], c0);
      c1 = fmaf(featq[i + 1], Wp[(size_t)(i + 1) * 400], c1);
      c2 = fmaf(featq[i + 2], Wp[(size_t)(i + 2) * 400], c2);
      c3 = fmaf(featq[i + 3], Wp[(size_t)(i + 3) * 400], c3);
    }
    hpart[(size_t)bq * 400 + tid] = (c0 + c1) + (c2 + c3);
  }
}

// Kernel 3: combine quarters + bias + relu, 400x6 GEMV (6 waves with
// shuffle-reduce), 6-way softmax, constant avg_alpha fill.
__global__ void finish_kernel(const float* __restrict__ hpart,
                              const float* __restrict__ b1,
                              const float* __restrict__ W2,
                              const float* __restrict__ b2,
                              float* __restrict__ out) {
  __shared__ float h[400];
  __shared__ float logits[6];
  const int b = blockIdx.x;
  const int tid = threadIdx.x;

  // avg_alpha == 1/T exactly. Output region [B*6, B*6 + B*S).
  if (tid < S) out[B * 6 + b * S + tid] = 1.0f / 128.0f;

  if (tid < 400) {
    const float* p = hpart + (size_t)b * 4 * 400 + tid;
    const float v = b1[tid] + ((p[0] + p[400]) + (p[800] + p[1200]));
    h[tid] = fmaxf(v, 0.f);
  }
  __syncthreads();

  if (tid < 6 * 64) {              // wave k computes logits[k]
    const int k = tid >> 6;
    const int lane = tid & 63;
    float acc = 0.f;
    for (int j = lane; j < 400; j += 64) acc = fmaf(h[j], W2[(size_t)j * 6 + k], acc);
    #pragma unroll
    for (int off = 32; off; off >>= 1) acc += __shfl_down(acc, off);
    if (lane == 0) logits[k] = acc + b2[k];
  }
  __syncthreads();

  if (tid == 0) {
    float m = logits[0];
    for (int k = 1; k < 6; ++k) m = fmaxf(m, logits[k]);
    float e[6], ssum = 0.f;
    for (int k = 0; k < 6; ++k) { e[k] = expf(logits[k] - m); ssum += e[k]; }
    const float inv = 1.0f / ssum;
    for (int k = 0; k < 6; ++k) out[b * 6 + k] = e[k] * inv;
  }
}

extern "C" void kernel_launch(void* const* d_in, const int* in_sizes, int n_in,
                              void* d_out, int out_size, void* d_ws, size_t ws_size,
                              hipStream_t stream) {
  const int*   text_ids  = (const int*)d_in[0];
  const int*   text_lens = (const int*)d_in[1];
  const int*   law_ids   = (const int*)d_in[2];
  const float* emb       = (const float*)d_in[3];
  const float* W1        = (const float*)d_in[4];
  const float* b1        = (const float*)d_in[5];
  const float* W2        = (const float*)d_in[6];
  const float* b2        = (const float*)d_in[7];
  float* out = (float*)d_out;

  float* fact_part = (float*)d_ws;                       // NTXT*D floats
  float* law_part  = fact_part + (size_t)NTXT * D;       // CHL*D floats
  float* hpart     = law_part + (size_t)CHL * D;         // B*4*400 floats
  // total ws: (2048*200 + 32*200 + 256*400) * 4 B ~= 2.07 MB

  hipLaunchKernelGGL(gather_sum_kernel, dim3(NTXT + CHL), dim3(256), 0, stream,
                     text_ids, text_lens, law_ids, emb, fact_part, law_part);
  hipLaunchKernelGGL(gemv_part_kernel, dim3(B * 4), dim3(512), 0, stream,
                     fact_part, law_part, W1, hpart);
  hipLaunchKernelGGL(finish_kernel, dim3(B), dim3(512), 0, stream,
                     hpart, b1, W2, b2, out);
}